// Round 9
// baseline (369.200 us; speedup 1.0000x reference)
//
#include <hip/hip_runtime.h>

#define IN_H 256
#define IN_W 256
#define C0   3
#define C1   32
#define H1   128
#define C2   64
#define H2   64
#define NB   32
#define K_FLAT (H2*H2*C2)   // 262144
#define NHID 128

// a1 layout: [b][parity 2][y 128][ci 32][x2 64], x = 2*x2 + parity.
#define A1_IDX(b,p,y,ci,x2) ((((((size_t)(b)*2 + (p))*H1 + (y))*C1 + (ci))*64) + (x2))

// ---------------------------------------------------------------- conv1
// in [32,256,256,3] -> a1p (planar layout above), stride2 SAME, ReLU.
__global__ __launch_bounds__(256, 8)
void conv1_k(const float* __restrict__ in, const float* __restrict__ k1,
             const float* __restrict__ b1, float* __restrict__ a1p) {
  __shared__ __align__(16) float rowL[3*IN_W*C0];   // 3 rows x 768 = 9216 B
  const int tid = threadIdx.x;
  const int oy  = blockIdx.x;       // 0..127
  const int b   = blockIdx.y;       // 0..31

  // stage 3 input rows (576 float4 total, 2.25/thread)
  {
    const float4* src = (const float4*)(in + (size_t)(b*IN_H + 2*oy)*IN_W*C0);
    float4* dst = (float4*)rowL;
    const float4 z = make_float4(0.f,0.f,0.f,0.f);
#pragma unroll
    for (int j = 0; j < 3; ++j) {
      const int i = tid + j*256;            // 0..767, need <576
      if (i < 3*IN_W*C0/4) {
        const int row = i / (IN_W*C0/4);    // 0..2
        const bool ok = (2*oy + row) < IN_H;  // block-uniform except oy=127
        dst[i] = ok ? src[i] : z;           // src rows are contiguous in b-image
      }
    }
  }
  __syncthreads();

  const int ox  = tid & 127;                                       // 0..127
  const int cg  = __builtin_amdgcn_readfirstlane((tid >> 7) * 16); // 0 or 16

  float acc[16];
#pragma unroll
  for (int co = 0; co < 16; ++co) acc[co] = b1[cg + co];

#pragma unroll
  for (int dy = 0; dy < 3; ++dy) {
#pragma unroll
    for (int dx = 0; dx < 3; ++dx) {
      const int ix  = 2*ox + dx;
      const bool ok = ix < IN_W;     // per-lane only for ox==127, dx==2
      const float m  = ok ? 1.f : 0.f;
      const int ixc = ok ? ix : (IN_W-1);
      const float* lp = rowL + (dy*IN_W + ixc)*C0;
      const float v0 = lp[0] * m;
      const float v1 = lp[1] * m;
      const float v2 = lp[2] * m;
      const float* wp = k1 + (size_t)((dy*3+dx)*C0)*C1 + cg;   // [ci][co]
#pragma unroll
      for (int co = 0; co < 16; ++co)
        acc[co] = fmaf(v0, wp[co],
                  fmaf(v1, wp[C1+co],
                  fmaf(v2, wp[2*C1+co], acc[co])));
    }
  }
  const int p  = ox & 1;
  const int x2 = ox >> 1;
#pragma unroll
  for (int co = 0; co < 16; ++co)
    a1p[A1_IDX(b, p, oy, cg + co, x2)] = fmaxf(acc[co], 0.f);
}

// ---------------------------------------------------------------- conv2
// a1p (planar) -> a2 [32,64,64,64] NHWC, stride2 SAME, ReLU.
// v4 = v2 structure + __launch_bounds__(256,4) + unroll 8 (R4: worked).
#define CONV2_DY_LOOP(EDGE_)                                                   \
  _Pragma("unroll")                                                            \
  for (int dy = 0; dy < 3; ++dy) {                                             \
    int iy = 2*oy + dy;                                                        \
    float rm = 1.f;                                                            \
    if (EDGE_) { if (iy >= H1) { iy = H1 - 1; rm = 0.f; } }                    \
    const float* r0 = a1p + A1_IDX(b, 0, iy, 0, 0) + 2*lx;                     \
    const float* r1 = a1p + A1_IDX(b, 1, iy, 0, 0) + 2*lx;                     \
    const float* wp = k2 + (size_t)(dy*3*C1)*C2 + cg16;                        \
    const float m2 = EDGE_ ? rm * xm : xm;                                     \
    _Pragma("unroll 8")                                                        \
    for (int ci = 0; ci < C1; ++ci) {                                          \
      const float2 Av = *(const float2*)(r0 + (size_t)ci*64);                  \
      const float  A2 = r0[(size_t)ci*64 + 2];                                 \
      const float2 Bv = *(const float2*)(r1 + (size_t)ci*64);                  \
      const float ax = EDGE_ ? Av.x*rm : Av.x;                                 \
      const float ay = EDGE_ ? Av.y*rm : Av.y;                                 \
      const float bx = EDGE_ ? Bv.x*rm : Bv.x;                                 \
      const float by = EDGE_ ? Bv.y*rm : Bv.y;                                 \
      const float a2v = A2 * m2;                                               \
      const float* w0  = wp + (size_t)ci*C2;                                   \
      const float* w1r = wp + (size_t)(C1 + ci)*C2;                            \
      const float* w2r = wp + (size_t)(2*C1 + ci)*C2;                          \
      _Pragma("unroll")                                                        \
      for (int co = 0; co < 16; ++co) {                                        \
        acc0[co] = fmaf(ax, w0[co],                                            \
                   fmaf(bx, w1r[co],                                           \
                   fmaf(ay,  w2r[co], acc0[co])));                             \
        acc1[co] = fmaf(ay, w0[co],                                            \
                   fmaf(by, w1r[co],                                           \
                   fmaf(a2v, w2r[co], acc1[co])));                             \
      }                                                                        \
    }                                                                          \
  }

__global__ __launch_bounds__(256, 4)
void conv2_k(const float* __restrict__ a1p, const float* __restrict__ k2,
             const float* __restrict__ b2, float* __restrict__ a2) {
  const int tid  = threadIdx.x;
  const int lane = tid & 63;
  const int lx   = lane & 31;                                       // ox pair
  const int oys  = lane >> 5;                                       // 0/1
  const int cg16 = __builtin_amdgcn_readfirstlane((tid >> 6) * 16); // co base
  const int oy   = blockIdx.x * 2 + oys;                            // 0..63
  const int b    = blockIdx.y;

  float acc0[16], acc1[16];
#pragma unroll
  for (int co = 0; co < 16; ++co) { acc0[co] = b2[cg16 + co]; acc1[co] = acc0[co]; }

  // ox1 = 2lx+1 == 63 has its dx=2 tap at x=128 (SAME pad) -> masked.
  const float xm = (lx == 31) ? 0.f : 1.f;

  if (blockIdx.x == 31) {            // contains oy=63: dy=2 row invalid (per-lane)
    CONV2_DY_LOOP(1)
  } else {
    CONV2_DY_LOOP(0)
  }

  float* op = a2 + ((size_t)((b*H2 + oy)*H2) + 2*lx)*C2 + cg16;
#pragma unroll
  for (int g = 0; g < 4; ++g) {
    float4 o0;
    o0.x = fmaxf(acc0[4*g+0], 0.f);
    o0.y = fmaxf(acc0[4*g+1], 0.f);
    o0.z = fmaxf(acc0[4*g+2], 0.f);
    o0.w = fmaxf(acc0[4*g+3], 0.f);
    ((float4*)op)[g] = o0;
    float4 o1;
    o1.x = fmaxf(acc1[4*g+0], 0.f);
    o1.y = fmaxf(acc1[4*g+1], 0.f);
    o1.z = fmaxf(acc1[4*g+2], 0.f);
    o1.w = fmaxf(acc1[4*g+3], 0.f);
    ((float4*)(op + C2))[g] = o1;
  }
}

// ---------------------------------------------------------------- FC1 partial
// x = a2 flat [32, 262144]; w1 [262144, 128].
// v6 (R8 post-mortem: v5's LDS-intensity fix was neutral -> the binding
// constraint is STAGE/COMPUTE PHASE SERIALIZATION: during each round's pure-
// LDS compute the block issues zero global traffic, and 3 blocks/CU give poor
// cross-block overlap -> HBM duty cycle ~60%). Fix = T14 async-STAGE split:
// issue round-1's global loads into registers BEFORE computing round 0
// (HBM latency hides under the ~4600-cyc FMA block), then reg->LDS after the
// barrier. Keeps v5's 8b x 8n tile + half-split wL + 4-way k-split + tree
// reduction.
#define FC1_G   2048
#define KSPAN   (K_FLAT / FC1_G)   // 128
#define SUB     64                 // k sub-round (2 rounds/block)
#define XSTR    40
#define GC1     16                 // reduce1 column-groups

__global__ __launch_bounds__(256, 3)
void fc1_partial_k(const float* __restrict__ a2, const float* __restrict__ w1,
                   float* __restrict__ partial) {
  __shared__ __align__(16) float wL[SUB*NHID];   // 32,768 B (also epilogue scratch)
  __shared__ __align__(16) float xT[SUB*XSTR];   // 10,240 B
  const int tid  = threadIdx.x;
  const int w    = tid >> 6;    // wave 0..3 -> k-quarter
  const int lane = tid & 63;
  const int nq   = lane & 15;   // n-octet: n = 8nq..8nq+7
  const int bq   = lane >> 4;   // b-octet: b = 8bq..8bq+7
  const int k0   = blockIdx.x * KSPAN;
  const int lb   = tid >> 3;    // 0..31 (x-stage)
  const int lkq  = tid & 7;     //        (x-stage)

  float acc[8][8];
#pragma unroll
  for (int i = 0; i < 8; ++i)
#pragma unroll
    for (int j = 0; j < 8; ++j) acc[i][j] = 0.f;

  float4 wr[8], xr[2];

  // ---- load round 0 into regs ----
  {
    const float4* wsrc = (const float4*)(w1 + (size_t)k0*NHID);
#pragma unroll
    for (int j = 0; j < 8; ++j) wr[j] = wsrc[tid + j*256];
#pragma unroll
    for (int j = 0; j < 2; ++j)
      xr[j] = *(const float4*)(a2 + (size_t)lb*K_FLAT + k0 + lkq*4 + j*32);
  }
  // ---- write round 0 to LDS ----
#pragma unroll
  for (int j = 0; j < 8; ++j) {
    const int i    = tid + j*256;     // 0..2047
    const int krow = i >> 5;
    const int qsrc = i & 31;
    const int qdst = (qsrc & 1) ? 16 + (qsrc >> 1) : (qsrc >> 1);
    ((float4*)wL)[krow*32 + qdst] = wr[j];
  }
#pragma unroll
  for (int j = 0; j < 2; ++j) {
    const int k4 = lkq*4 + j*32;
    xT[(k4+0)*XSTR + lb] = xr[j].x;
    xT[(k4+1)*XSTR + lb] = xr[j].y;
    xT[(k4+2)*XSTR + lb] = xr[j].z;
    xT[(k4+3)*XSTR + lb] = xr[j].w;
  }
  // ---- issue round 1 loads (in flight across round-0 compute) ----
  {
    const int ks = k0 + SUB;
    const float4* wsrc = (const float4*)(w1 + (size_t)ks*NHID);
#pragma unroll
    for (int j = 0; j < 8; ++j) wr[j] = wsrc[tid + j*256];
#pragma unroll
    for (int j = 0; j < 2; ++j)
      xr[j] = *(const float4*)(a2 + (size_t)lb*K_FLAT + ks + lkq*4 + j*32);
  }
  __syncthreads();   // LDS round 0 ready

  // ---- compute round 0 (this wave's k-quarter) ----
#pragma unroll 2
  for (int kk = 0; kk < SUB/4; ++kk) {
    const int k = w*(SUB/4) + kk;
    const float4 wa  = ((const float4*)wL)[k*32 + nq];
    const float4 wb  = ((const float4*)wL)[k*32 + 16 + nq];
    const float4 xa  = *(const float4*)&xT[k*XSTR + 8*bq];
    const float4 xb4 = *(const float4*)&xT[k*XSTR + 8*bq + 4];
    const float xv[8] = {xa.x, xa.y, xa.z, xa.w, xb4.x, xb4.y, xb4.z, xb4.w};
    const float wv[8] = {wa.x, wa.y, wa.z, wa.w, wb.x, wb.y, wb.z, wb.w};
#pragma unroll
    for (int i = 0; i < 8; ++i)
#pragma unroll
      for (int j = 0; j < 8; ++j)
        acc[i][j] = fmaf(xv[i], wv[j], acc[i][j]);
  }
  __syncthreads();   // all round-0 LDS reads done

  // ---- write round 1 to LDS (loads landed during compute) ----
#pragma unroll
  for (int j = 0; j < 8; ++j) {
    const int i    = tid + j*256;
    const int krow = i >> 5;
    const int qsrc = i & 31;
    const int qdst = (qsrc & 1) ? 16 + (qsrc >> 1) : (qsrc >> 1);
    ((float4*)wL)[krow*32 + qdst] = wr[j];
  }
#pragma unroll
  for (int j = 0; j < 2; ++j) {
    const int k4 = lkq*4 + j*32;
    xT[(k4+0)*XSTR + lb] = xr[j].x;
    xT[(k4+1)*XSTR + lb] = xr[j].y;
    xT[(k4+2)*XSTR + lb] = xr[j].z;
    xT[(k4+3)*XSTR + lb] = xr[j].w;
  }
  __syncthreads();   // LDS round 1 ready

  // ---- compute round 1 ----
#pragma unroll 2
  for (int kk = 0; kk < SUB/4; ++kk) {
    const int k = w*(SUB/4) + kk;
    const float4 wa  = ((const float4*)wL)[k*32 + nq];
    const float4 wb  = ((const float4*)wL)[k*32 + 16 + nq];
    const float4 xa  = *(const float4*)&xT[k*XSTR + 8*bq];
    const float4 xb4 = *(const float4*)&xT[k*XSTR + 8*bq + 4];
    const float xv[8] = {xa.x, xa.y, xa.z, xa.w, xb4.x, xb4.y, xb4.z, xb4.w};
    const float wv[8] = {wa.x, wa.y, wa.z, wa.w, wb.x, wb.y, wb.z, wb.w};
#pragma unroll
    for (int i = 0; i < 8; ++i)
#pragma unroll
      for (int j = 0; j < 8; ++j)
        acc[i][j] = fmaf(xv[i], wv[j], acc[i][j]);
  }

  // ---- cross-wave tree reduction through LDS (wL reused as scratch) ----
  float* s0 = wL;            // 4096 floats
  float* s1 = wL + 4096;     // 4096 floats
  __syncthreads();                       // all compute reads of wL/xT done
  if (w == 1 || w == 3) {
    float* s = (w == 1) ? s0 : s1;
#pragma unroll
    for (int i = 0; i < 8; ++i)
#pragma unroll
      for (int j = 0; j < 8; ++j) s[(i*8+j)*64 + lane] = acc[i][j];
  }
  __syncthreads();
  if (w == 0 || w == 2) {
    const float* s = (w == 0) ? s0 : s1;
#pragma unroll
    for (int i = 0; i < 8; ++i)
#pragma unroll
      for (int j = 0; j < 8; ++j) acc[i][j] += s[(i*8+j)*64 + lane];
  }
  __syncthreads();
  if (w == 2) {
#pragma unroll
    for (int i = 0; i < 8; ++i)
#pragma unroll
      for (int j = 0; j < 8; ++j) s0[(i*8+j)*64 + lane] = acc[i][j];
  }
  __syncthreads();
  if (w == 0) {
#pragma unroll
    for (int i = 0; i < 8; ++i)
#pragma unroll
      for (int j = 0; j < 8; ++j) acc[i][j] += s0[(i*8+j)*64 + lane];
    // store partial[block][b][n]: per i, 8 consecutive n -> 2 float4
    float* pp = partial + (size_t)blockIdx.x*(NB*NHID);
#pragma unroll
    for (int i = 0; i < 8; ++i) {
      float4 o0 = make_float4(acc[i][0], acc[i][1], acc[i][2], acc[i][3]);
      float4 o1 = make_float4(acc[i][4], acc[i][5], acc[i][6], acc[i][7]);
      float* row = pp + (size_t)(8*bq + i)*NHID + 8*nq;
      *(float4*)(row)     = o0;
      *(float4*)(row + 4) = o1;
    }
  }
}

// ---------------------------------------------------------------- FC1 reduce stage 1: 2048 -> 16
__global__ __launch_bounds__(128, 8)
void fc1_reduce1_k(const float* __restrict__ partial, float* __restrict__ partial2) {
  const int t  = blockIdx.x*128 + threadIdx.x;  // 0..4095
  const int gc = blockIdx.y;                    // 0..15
  float s = 0.f;
#pragma unroll 8
  for (int g = gc*(FC1_G/GC1); g < gc*(FC1_G/GC1) + (FC1_G/GC1); ++g)
    s += partial[(size_t)g*(NB*NHID) + t];
  partial2[(size_t)gc*(NB*NHID) + t] = s;
}

// ---------------------------------------------------------------- FC1 reduce stage 2 (+bias+ReLU)
__global__ __launch_bounds__(256)
void fc1_reduce2_k(const float* __restrict__ partial2, const float* __restrict__ d1,
                   float* __restrict__ h) {
  const int t = blockIdx.x*256 + threadIdx.x;  // 0..4095
  float s = 0.f;
#pragma unroll
  for (int gc = 0; gc < GC1; ++gc) s += partial2[(size_t)gc*(NB*NHID) + t];
  h[t] = fmaxf(s + d1[t & (NHID-1)], 0.f);
}

// ---------------------------------------------------------------- theta = h @ w2 + d2
__global__ __launch_bounds__(192)
void theta_k(const float* __restrict__ h, const float* __restrict__ w2,
             const float* __restrict__ d2, float* __restrict__ theta) {
  const int t = threadIdx.x;
  if (t >= NB*6) return;
  const int b = t / 6, j = t % 6;
  float s0 = 0.f, s1 = 0.f, s2 = 0.f, s3 = 0.f;
  for (int n = 0; n < NHID; n += 4) {
    s0 = fmaf(h[b*NHID + n+0], w2[(n+0)*6 + j], s0);
    s1 = fmaf(h[b*NHID + n+1], w2[(n+1)*6 + j], s1);
    s2 = fmaf(h[b*NHID + n+2], w2[(n+2)*6 + j], s2);
    s3 = fmaf(h[b*NHID + n+3], w2[(n+3)*6 + j], s3);
  }
  theta[t] = (s0 + s1) + (s2 + s3) + d2[j];
}

// ---------------------------------------------------------------- grid sample (bilinear, zero pad)
__global__ __launch_bounds__(256)
void sample_k(const float* __restrict__ img, const float* __restrict__ theta,
              float* __restrict__ out) {
  const int x = threadIdx.x;
  const int y = blockIdx.x & (IN_H-1);
  const int b = blockIdx.x >> 8;
  const float* tp = theta + b*6;
  const float t0 = tp[0], t1 = tp[1], t2 = tp[2];
  const float t3 = tp[3], t4 = tp[4], t5 = tp[5];

  const float xs = (2.f*x + 1.f)*(1.f/IN_W) - 1.f;
  const float ys = (2.f*y + 1.f)*(1.f/IN_H) - 1.f;
  const float gx = fmaf(t0, xs, fmaf(t1, ys, t2));
  const float gy = fmaf(t3, xs, fmaf(t4, ys, t5));
  const float px = fmaf(gx + 1.f, 0.5f*IN_W, -0.5f);
  const float py = fmaf(gy + 1.f, 0.5f*IN_H, -0.5f);

  const float x0f = floorf(px), y0f = floorf(py);
  const int ix0 = (int)x0f, iy0 = (int)y0f;
  const float wx1 = px - x0f, wx0 = 1.f - wx1;
  const float wy1 = py - y0f, wy0 = 1.f - wy1;

  float r = 0.f, g = 0.f, bl = 0.f;
  const float* ib = img + (size_t)b*IN_H*IN_W*C0;

  auto tap = [&](int yi, int xi, float w) {
    const bool v = (xi >= 0) && (xi < IN_W) && (yi >= 0) && (yi < IN_H);
    const int xc = xi < 0 ? 0 : (xi > IN_W-1 ? IN_W-1 : xi);
    const int yc = yi < 0 ? 0 : (yi > IN_H-1 ? IN_H-1 : yi);
    const float* p = ib + ((size_t)yc*IN_W + xc)*C0;
    if (v) {
      r  = fmaf(w, p[0], r);
      g  = fmaf(w, p[1], g);
      bl = fmaf(w, p[2], bl);
    }
  };
  tap(iy0,   ix0,   wy0*wx0);
  tap(iy0,   ix0+1, wy0*wx1);
  tap(iy0+1, ix0,   wy1*wx0);
  tap(iy0+1, ix0+1, wy1*wx1);

  float* op = out + ((size_t)(b*IN_H + y)*IN_W + x)*C0;
  op[0] = r; op[1] = g; op[2] = bl;
}

// ---------------------------------------------------------------- launch
extern "C" void kernel_launch(void* const* d_in, const int* in_sizes, int n_in,
                              void* d_out, int out_size, void* d_ws, size_t ws_size,
                              hipStream_t stream) {
  const float* in = (const float*)d_in[0];
  const float* k1 = (const float*)d_in[1];
  const float* b1 = (const float*)d_in[2];
  const float* k2 = (const float*)d_in[3];
  const float* b2 = (const float*)d_in[4];
  const float* w1 = (const float*)d_in[5];
  const float* d1 = (const float*)d_in[6];
  const float* w2 = (const float*)d_in[7];
  const float* d2 = (const float*)d_in[8];
  float* out = (float*)d_out;
  float* ws  = (float*)d_ws;

  // ws layout (float offsets):
  //   a1p      [16,777,216] @ 0               (planar, exactly 64 MB)
  //   a2       [ 8,388,608] @ 16,777,216      (NHWC, matches flatten order)
  //   -- after conv2, a1p region is dead and reused: --
  //   partial  [2048*4096 = 8,388,608] @ 0
  //   partial2 [16*4096   =    65,536] @ 8,388,608
  //   h        [4096]                  @ 8,454,144
  //   theta    [192]                   @ 8,458,240
  float* a1p     = ws;
  float* a2      = ws + (size_t)16777216;
  float* partial = ws;
  float* part2   = ws + (size_t)8388608;
  float* h       = ws + (size_t)8454144;
  float* th      = ws + (size_t)8458240;

  hipLaunchKernelGGL(conv1_k,       dim3(128, 32), dim3(256), 0, stream, in, k1, b1, a1p);
  hipLaunchKernelGGL(conv2_k,       dim3(32, 32),  dim3(256), 0, stream, a1p, k2, b2, a2);
  hipLaunchKernelGGL(fc1_partial_k, dim3(FC1_G),   dim3(256), 0, stream, a2, w1, partial);
  hipLaunchKernelGGL(fc1_reduce1_k, dim3(32, GC1), dim3(128), 0, stream, partial, part2);
  hipLaunchKernelGGL(fc1_reduce2_k, dim3(16),      dim3(256), 0, stream, part2, d1, h);
  hipLaunchKernelGGL(theta_k,       dim3(1),       dim3(192), 0, stream, h, w2, d2, th);
  hipLaunchKernelGGL(sample_k,      dim3(NB*IN_H), dim3(256), 0, stream, in, th, out);
}

// Round 10
// 346.296 us; speedup vs baseline: 1.0661x; 1.0661x over previous
//
#include <hip/hip_runtime.h>

#define IN_H 256
#define IN_W 256
#define C0   3
#define C1   32
#define H1   128
#define C2   64
#define H2   64
#define NB   32
#define K_FLAT (H2*H2*C2)   // 262144
#define NHID 128

// a1 layout: [b][parity 2][y 128][ci 32][x2 64], x = 2*x2 + parity.
#define A1_IDX(b,p,y,ci,x2) ((((((size_t)(b)*2 + (p))*H1 + (y))*C1 + (ci))*64) + (x2))

// ---------------------------------------------------------------- conv1
// in [32,256,256,3] -> a1p (planar layout above), stride2 SAME, ReLU.
__global__ __launch_bounds__(256, 8)
void conv1_k(const float* __restrict__ in, const float* __restrict__ k1,
             const float* __restrict__ b1, float* __restrict__ a1p) {
  __shared__ __align__(16) float rowL[3*IN_W*C0];   // 3 rows x 768 = 9216 B
  const int tid = threadIdx.x;
  const int oy  = blockIdx.x;       // 0..127
  const int b   = blockIdx.y;       // 0..31

  // stage 3 input rows (576 float4 total, 2.25/thread)
  {
    const float4* src = (const float4*)(in + (size_t)(b*IN_H + 2*oy)*IN_W*C0);
    float4* dst = (float4*)rowL;
    const float4 z = make_float4(0.f,0.f,0.f,0.f);
#pragma unroll
    for (int j = 0; j < 3; ++j) {
      const int i = tid + j*256;            // 0..767, need <576
      if (i < 3*IN_W*C0/4) {
        const int row = i / (IN_W*C0/4);    // 0..2
        const bool ok = (2*oy + row) < IN_H;  // block-uniform except oy=127
        dst[i] = ok ? src[i] : z;           // src rows are contiguous in b-image
      }
    }
  }
  __syncthreads();

  const int ox  = tid & 127;                                       // 0..127
  const int cg  = __builtin_amdgcn_readfirstlane((tid >> 7) * 16); // 0 or 16

  float acc[16];
#pragma unroll
  for (int co = 0; co < 16; ++co) acc[co] = b1[cg + co];

#pragma unroll
  for (int dy = 0; dy < 3; ++dy) {
#pragma unroll
    for (int dx = 0; dx < 3; ++dx) {
      const int ix  = 2*ox + dx;
      const bool ok = ix < IN_W;     // per-lane only for ox==127, dx==2
      const float m  = ok ? 1.f : 0.f;
      const int ixc = ok ? ix : (IN_W-1);
      const float* lp = rowL + (dy*IN_W + ixc)*C0;
      const float v0 = lp[0] * m;
      const float v1 = lp[1] * m;
      const float v2 = lp[2] * m;
      const float* wp = k1 + (size_t)((dy*3+dx)*C0)*C1 + cg;   // [ci][co]
#pragma unroll
      for (int co = 0; co < 16; ++co)
        acc[co] = fmaf(v0, wp[co],
                  fmaf(v1, wp[C1+co],
                  fmaf(v2, wp[2*C1+co], acc[co])));
    }
  }
  const int p  = ox & 1;
  const int x2 = ox >> 1;
#pragma unroll
  for (int co = 0; co < 16; ++co)
    a1p[A1_IDX(b, p, oy, cg + co, x2)] = fmaxf(acc[co], 0.f);
}

// ---------------------------------------------------------------- conv2
// a1p (planar) -> a2 [32,64,64,64] NHWC, stride2 SAME, ReLU.
// v4 = v2 structure + __launch_bounds__(256,4) + unroll 8 (R4: worked).
#define CONV2_DY_LOOP(EDGE_)                                                   \
  _Pragma("unroll")                                                            \
  for (int dy = 0; dy < 3; ++dy) {                                             \
    int iy = 2*oy + dy;                                                        \
    float rm = 1.f;                                                            \
    if (EDGE_) { if (iy >= H1) { iy = H1 - 1; rm = 0.f; } }                    \
    const float* r0 = a1p + A1_IDX(b, 0, iy, 0, 0) + 2*lx;                     \
    const float* r1 = a1p + A1_IDX(b, 1, iy, 0, 0) + 2*lx;                     \
    const float* wp = k2 + (size_t)(dy*3*C1)*C2 + cg16;                        \
    const float m2 = EDGE_ ? rm * xm : xm;                                     \
    _Pragma("unroll 8")                                                        \
    for (int ci = 0; ci < C1; ++ci) {                                          \
      const float2 Av = *(const float2*)(r0 + (size_t)ci*64);                  \
      const float  A2 = r0[(size_t)ci*64 + 2];                                 \
      const float2 Bv = *(const float2*)(r1 + (size_t)ci*64);                  \
      const float ax = EDGE_ ? Av.x*rm : Av.x;                                 \
      const float ay = EDGE_ ? Av.y*rm : Av.y;                                 \
      const float bx = EDGE_ ? Bv.x*rm : Bv.x;                                 \
      const float by = EDGE_ ? Bv.y*rm : Bv.y;                                 \
      const float a2v = A2 * m2;                                               \
      const float* w0  = wp + (size_t)ci*C2;                                   \
      const float* w1r = wp + (size_t)(C1 + ci)*C2;                            \
      const float* w2r = wp + (size_t)(2*C1 + ci)*C2;                          \
      _Pragma("unroll")                                                        \
      for (int co = 0; co < 16; ++co) {                                        \
        acc0[co] = fmaf(ax, w0[co],                                            \
                   fmaf(bx, w1r[co],                                           \
                   fmaf(ay,  w2r[co], acc0[co])));                             \
        acc1[co] = fmaf(ay, w0[co],                                            \
                   fmaf(by, w1r[co],                                           \
                   fmaf(a2v, w2r[co], acc1[co])));                             \
      }                                                                        \
    }                                                                          \
  }

__global__ __launch_bounds__(256, 4)
void conv2_k(const float* __restrict__ a1p, const float* __restrict__ k2,
             const float* __restrict__ b2, float* __restrict__ a2) {
  const int tid  = threadIdx.x;
  const int lane = tid & 63;
  const int lx   = lane & 31;                                       // ox pair
  const int oys  = lane >> 5;                                       // 0/1
  const int cg16 = __builtin_amdgcn_readfirstlane((tid >> 6) * 16); // co base
  const int oy   = blockIdx.x * 2 + oys;                            // 0..63
  const int b    = blockIdx.y;

  float acc0[16], acc1[16];
#pragma unroll
  for (int co = 0; co < 16; ++co) { acc0[co] = b2[cg16 + co]; acc1[co] = acc0[co]; }

  // ox1 = 2lx+1 == 63 has its dx=2 tap at x=128 (SAME pad) -> masked.
  const float xm = (lx == 31) ? 0.f : 1.f;

  if (blockIdx.x == 31) {            // contains oy=63: dy=2 row invalid (per-lane)
    CONV2_DY_LOOP(1)
  } else {
    CONV2_DY_LOOP(0)
  }

  float* op = a2 + ((size_t)((b*H2 + oy)*H2) + 2*lx)*C2 + cg16;
#pragma unroll
  for (int g = 0; g < 4; ++g) {
    float4 o0;
    o0.x = fmaxf(acc0[4*g+0], 0.f);
    o0.y = fmaxf(acc0[4*g+1], 0.f);
    o0.z = fmaxf(acc0[4*g+2], 0.f);
    o0.w = fmaxf(acc0[4*g+3], 0.f);
    ((float4*)op)[g] = o0;
    float4 o1;
    o1.x = fmaxf(acc1[4*g+0], 0.f);
    o1.y = fmaxf(acc1[4*g+1], 0.f);
    o1.z = fmaxf(acc1[4*g+2], 0.f);
    o1.w = fmaxf(acc1[4*g+3], 0.f);
    ((float4*)(op + C2))[g] = o1;
  }
}

// ---------------------------------------------------------------- FC1 partial
// x = a2 flat [32, 262144]; w1 [262144, 128].
// v4 AGAIN (R9 post-mortem: T14 reg double-buffer REGRESSED 349.6->369.2 —
// the in-flight regs + 2 extra barriers cost more than the prefetch hid.
// This is the best-measured fc1 structure: R6 total 348.8). Stage BOTH
// operands in LDS per 64-k sub-round; bulk MLP staging; pure-LDS FMA loop.
#define FC1_G   2048
#define KSPAN   (K_FLAT / FC1_G)   // 128
#define SUB     64                 // k sub-round
#define GC1     16                 // reduce1 column-groups

__global__ __launch_bounds__(256, 3)
void fc1_partial_k(const float* __restrict__ a2, const float* __restrict__ w1,
                   float* __restrict__ partial) {
  __shared__ __align__(16) float wL[SUB*NHID];   // 32,768 B
  __shared__ __align__(16) float xT[SUB*36];     //  9,216 B
  const int tid = threadIdx.x;
  const int q   = tid & 31;    // n-quad: n = 4q..4q+3
  const int bo  = tid >> 5;    // 0..7 : b = 4bo..4bo+3
  const int k0  = blockIdx.x * KSPAN;

  float4 a0 = make_float4(0.f,0.f,0.f,0.f), a1v = a0, a2v = a0, a3v = a0;

#pragma unroll
  for (int r = 0; r < KSPAN/SUB; ++r) {
    const int ks = k0 + r*SUB;
    if (r) __syncthreads();          // protect LDS reuse across rounds

    // stage w1 chunk [SUB][128] linearly: 2048 float4, 8 per thread
    {
      const float4* wsrc = (const float4*)(w1 + (size_t)ks*NHID);
#pragma unroll
      for (int j = 0; j < 8; ++j)
        ((float4*)wL)[tid + j*256] = wsrc[tid + j*256];
    }
    // stage x chunk transposed: xT[k][b]
    {
      const int lb  = tid >> 3;    // 0..31
      const int lkq = tid & 7;
#pragma unroll
      for (int j = 0; j < 2; ++j) {
        const int k4 = lkq*4 + j*32;
        float4 t = *(const float4*)(a2 + (size_t)lb*K_FLAT + ks + k4);
        xT[(k4+0)*36 + lb] = t.x;
        xT[(k4+1)*36 + lb] = t.y;
        xT[(k4+2)*36 + lb] = t.z;
        xT[(k4+3)*36 + lb] = t.w;
      }
    }
    __syncthreads();

#pragma unroll 8
    for (int k = 0; k < SUB; ++k) {
      const float4 w4 = *(const float4*)(wL + k*NHID + 4*q);
      const float4 xb = *(const float4*)&xT[k*36 + 4*bo];
      a0.x = fmaf(xb.x, w4.x, a0.x); a0.y = fmaf(xb.x, w4.y, a0.y);
      a0.z = fmaf(xb.x, w4.z, a0.z); a0.w = fmaf(xb.x, w4.w, a0.w);
      a1v.x = fmaf(xb.y, w4.x, a1v.x); a1v.y = fmaf(xb.y, w4.y, a1v.y);
      a1v.z = fmaf(xb.y, w4.z, a1v.z); a1v.w = fmaf(xb.y, w4.w, a1v.w);
      a2v.x = fmaf(xb.z, w4.x, a2v.x); a2v.y = fmaf(xb.z, w4.y, a2v.y);
      a2v.z = fmaf(xb.z, w4.z, a2v.z); a2v.w = fmaf(xb.z, w4.w, a2v.w);
      a3v.x = fmaf(xb.w, w4.x, a3v.x); a3v.y = fmaf(xb.w, w4.y, a3v.y);
      a3v.z = fmaf(xb.w, w4.z, a3v.z); a3v.w = fmaf(xb.w, w4.w, a3v.w);
    }
  }

  float* pp = partial + (size_t)blockIdx.x*(NB*NHID) + 4*q;
  *(float4*)(pp + (4*bo+0)*NHID) = a0;
  *(float4*)(pp + (4*bo+1)*NHID) = a1v;
  *(float4*)(pp + (4*bo+2)*NHID) = a2v;
  *(float4*)(pp + (4*bo+3)*NHID) = a3v;
}

// ---------------------------------------------------------------- FC1 reduce stage 1: 2048 -> 16
__global__ __launch_bounds__(128, 8)
void fc1_reduce1_k(const float* __restrict__ partial, float* __restrict__ partial2) {
  const int t  = blockIdx.x*128 + threadIdx.x;  // 0..4095
  const int gc = blockIdx.y;                    // 0..15
  float s = 0.f;
#pragma unroll 8
  for (int g = gc*(FC1_G/GC1); g < gc*(FC1_G/GC1) + (FC1_G/GC1); ++g)
    s += partial[(size_t)g*(NB*NHID) + t];
  partial2[(size_t)gc*(NB*NHID) + t] = s;
}

// ---------------------------------------------------------------- FC1 reduce stage 2 (+bias+ReLU)
__global__ __launch_bounds__(256)
void fc1_reduce2_k(const float* __restrict__ partial2, const float* __restrict__ d1,
                   float* __restrict__ h) {
  const int t = blockIdx.x*256 + threadIdx.x;  // 0..4095
  float s = 0.f;
#pragma unroll
  for (int gc = 0; gc < GC1; ++gc) s += partial2[(size_t)gc*(NB*NHID) + t];
  h[t] = fmaxf(s + d1[t & (NHID-1)], 0.f);
}

// ---------------------------------------------------------------- theta = h @ w2 + d2
__global__ __launch_bounds__(192)
void theta_k(const float* __restrict__ h, const float* __restrict__ w2,
             const float* __restrict__ d2, float* __restrict__ theta) {
  const int t = threadIdx.x;
  if (t >= NB*6) return;
  const int b = t / 6, j = t % 6;
  float s0 = 0.f, s1 = 0.f, s2 = 0.f, s3 = 0.f;
  for (int n = 0; n < NHID; n += 4) {
    s0 = fmaf(h[b*NHID + n+0], w2[(n+0)*6 + j], s0);
    s1 = fmaf(h[b*NHID + n+1], w2[(n+1)*6 + j], s1);
    s2 = fmaf(h[b*NHID + n+2], w2[(n+2)*6 + j], s2);
    s3 = fmaf(h[b*NHID + n+3], w2[(n+3)*6 + j], s3);
  }
  theta[t] = (s0 + s1) + (s2 + s3) + d2[j];
}

// ---------------------------------------------------------------- grid sample (bilinear, zero pad)
// v2 (R9 accounting: sample ~40us vs ~10us floor; same no-launch-bounds +
// control-dependent-loads pathology as conv2/fc1 had). All 12 loads made
// unconditional (clamped coords are always in-bounds) and independent; the
// zero-pad validity is folded into the 4 tap WEIGHTS. launch_bounds(256,8)
// gives the ~12 load buffers room -> one latency exposure instead of four.
__global__ __launch_bounds__(256, 8)
void sample_k(const float* __restrict__ img, const float* __restrict__ theta,
              float* __restrict__ out) {
  const int x = threadIdx.x;
  const int y = blockIdx.x & (IN_H-1);
  const int b = blockIdx.x >> 8;
  const float* tp = theta + b*6;
  const float t0 = tp[0], t1 = tp[1], t2 = tp[2];
  const float t3 = tp[3], t4 = tp[4], t5 = tp[5];

  const float xs = (2.f*x + 1.f)*(1.f/IN_W) - 1.f;
  const float ys = (2.f*y + 1.f)*(1.f/IN_H) - 1.f;
  const float gx = fmaf(t0, xs, fmaf(t1, ys, t2));
  const float gy = fmaf(t3, xs, fmaf(t4, ys, t5));
  const float px = fmaf(gx + 1.f, 0.5f*IN_W, -0.5f);
  const float py = fmaf(gy + 1.f, 0.5f*IN_H, -0.5f);

  const float x0f = floorf(px), y0f = floorf(py);
  const int ix0 = (int)x0f, iy0 = (int)y0f;
  const int ix1 = ix0 + 1,  iy1 = iy0 + 1;
  const float wx1 = px - x0f, wx0 = 1.f - wx1;
  const float wy1 = py - y0f, wy0 = 1.f - wy1;

  // validity -> weights; clamped coords -> always-safe loads
  const float vx0 = (ix0 >= 0 && ix0 < IN_W) ? 1.f : 0.f;
  const float vx1 = (ix1 >= 0 && ix1 < IN_W) ? 1.f : 0.f;
  const float vy0 = (iy0 >= 0 && iy0 < IN_H) ? 1.f : 0.f;
  const float vy1 = (iy1 >= 0 && iy1 < IN_H) ? 1.f : 0.f;
  const int cx0 = ix0 < 0 ? 0 : (ix0 > IN_W-1 ? IN_W-1 : ix0);
  const int cx1 = ix1 < 0 ? 0 : (ix1 > IN_W-1 ? IN_W-1 : ix1);
  const int cy0 = iy0 < 0 ? 0 : (iy0 > IN_H-1 ? IN_H-1 : iy0);
  const int cy1 = iy1 < 0 ? 0 : (iy1 > IN_H-1 ? IN_H-1 : iy1);

  const float w00 = wy0*wx0 * vy0*vx0;
  const float w01 = wy0*wx1 * vy0*vx1;
  const float w10 = wy1*wx0 * vy1*vx0;
  const float w11 = wy1*wx1 * vy1*vx1;

  const float* ib  = img + (size_t)b*IN_H*IN_W*C0;
  const float* p00 = ib + ((size_t)cy0*IN_W + cx0)*C0;
  const float* p01 = ib + ((size_t)cy0*IN_W + cx1)*C0;
  const float* p10 = ib + ((size_t)cy1*IN_W + cx0)*C0;
  const float* p11 = ib + ((size_t)cy1*IN_W + cx1)*C0;

  // 12 independent loads, then combine
  const float r00 = p00[0], g00 = p00[1], b00 = p00[2];
  const float r01 = p01[0], g01 = p01[1], b01 = p01[2];
  const float r10 = p10[0], g10 = p10[1], b10 = p10[2];
  const float r11 = p11[0], g11 = p11[1], b11 = p11[2];

  const float r = fmaf(w00, r00, fmaf(w01, r01, fmaf(w10, r10, w11*r11)));
  const float g = fmaf(w00, g00, fmaf(w01, g01, fmaf(w10, g10, w11*g11)));
  const float bl= fmaf(w00, b00, fmaf(w01, b01, fmaf(w10, b10, w11*b11)));

  float* op = out + ((size_t)(b*IN_H + y)*IN_W + x)*C0;
  op[0] = r; op[1] = g; op[2] = bl;
}

// ---------------------------------------------------------------- launch
extern "C" void kernel_launch(void* const* d_in, const int* in_sizes, int n_in,
                              void* d_out, int out_size, void* d_ws, size_t ws_size,
                              hipStream_t stream) {
  const float* in = (const float*)d_in[0];
  const float* k1 = (const float*)d_in[1];
  const float* b1 = (const float*)d_in[2];
  const float* k2 = (const float*)d_in[3];
  const float* b2 = (const float*)d_in[4];
  const float* w1 = (const float*)d_in[5];
  const float* d1 = (const float*)d_in[6];
  const float* w2 = (const float*)d_in[7];
  const float* d2 = (const float*)d_in[8];
  float* out = (float*)d_out;
  float* ws  = (float*)d_ws;

  // ws layout (float offsets):
  //   a1p      [16,777,216] @ 0               (planar, exactly 64 MB)
  //   a2       [ 8,388,608] @ 16,777,216      (NHWC, matches flatten order)
  //   -- after conv2, a1p region is dead and reused: --
  //   partial  [2048*4096 = 8,388,608] @ 0
  //   partial2 [16*4096   =    65,536] @ 8,388,608
  //   h        [4096]                  @ 8,454,144
  //   theta    [192]                   @ 8,458,240
  float* a1p     = ws;
  float* a2      = ws + (size_t)16777216;
  float* partial = ws;
  float* part2   = ws + (size_t)8388608;
  float* h       = ws + (size_t)8454144;
  float* th      = ws + (size_t)8458240;

  hipLaunchKernelGGL(conv1_k,       dim3(128, 32), dim3(256), 0, stream, in, k1, b1, a1p);
  hipLaunchKernelGGL(conv2_k,       dim3(32, 32),  dim3(256), 0, stream, a1p, k2, b2, a2);
  hipLaunchKernelGGL(fc1_partial_k, dim3(FC1_G),   dim3(256), 0, stream, a2, w1, partial);
  hipLaunchKernelGGL(fc1_reduce1_k, dim3(32, GC1), dim3(128), 0, stream, partial, part2);
  hipLaunchKernelGGL(fc1_reduce2_k, dim3(16),      dim3(256), 0, stream, part2, d1, h);
  hipLaunchKernelGGL(theta_k,       dim3(1),       dim3(192), 0, stream, h, w2, d2, th);
  hipLaunchKernelGGL(sample_k,      dim3(NB*IN_H), dim3(256), 0, stream, in, th, out);
}